// Round 13
// baseline (274.503 us; speedup 1.0000x reference)
//
#include <hip/hip_runtime.h>
#include <math.h>

#define SQ 4096
#define DD 1024
#define TRI 528          // causal 128x128 tiles in a 32x32 grid

typedef _Float16 f16;
typedef f16 f16x8 __attribute__((ext_vector_type(8)));
typedef f16 f16x4 __attribute__((ext_vector_type(4)));
typedef float f32x4 __attribute__((ext_vector_type(4)));

__device__ __forceinline__ float waveMax(float v) {
#pragma unroll
    for (int o = 32; o > 0; o >>= 1) v = fmaxf(v, __shfl_down(v, o, 64));
    return v;
}
__device__ __forceinline__ float waveSum(float v) {
#pragma unroll
    for (int o = 32; o > 0; o >>= 1) v += __shfl_down(v, o, 64);
    return v;
}

__device__ __forceinline__ void gl_lds16(const f16* g, f16* l) {
    __builtin_amdgcn_global_load_lds(
        (const __attribute__((address_space(1))) void*)g,
        (__attribute__((address_space(3))) void*)l, 16, 0, 0);
}

// Wave w stages NRW rows of a [*,32] f16 tile into LDS row-major [rows][32].
// Plain layout (R3: swizzles neutral for 16x16 reads; R9 permutation regressed).
template<int NRW>
__device__ __forceinline__ void stage(const f16* src, int ldk, f16* lds, int w, int lane) {
    const int r0 = w * NRW + (lane >> 2);
    const f16* g = src + (size_t)r0 * ldk + ((lane & 3) << 3);
    f16* l = lds + w * NRW * 32;
#pragma unroll
    for (int i = 0; i < NRW / 16; ++i)
        gl_lds16(g + (size_t)ldk * (i << 4), l + (i << 4) * 32);
}

// Unified TN GEMM over K-contiguous f16 operands, 16x16x32 MFMA (proven best).
// Numerics (frozen as of R11): x-side split mandatory for Q/K (coherent error),
// W-side split unnecessary (iid error ~0.02 scaled), QK^T full split3.
// Tile-shape history: 64x128 (R4), BK=64 (R5), 256x128 (R12), 32x32 MFMA (R9),
// flatmm (R8) all fail to beat ~650 TF — the split3 structure plateau. 128x128
// with split-K=2 for residency (R6) is the verified optimum.
// __launch_bounds__(256,2) on ALL modes: +25 us on proj/PV (R12 A/B evidence).
// MODE 0: merged QKV projection, 128x128, BK=32, grid (24,32)=768 blocks (3/CU).
//         bn<16 (Q,K): x-split 2-MFMA + hi/lo split-store. bn>=16 (V): hi-only
//         + transposed f16 store. LDS 24 KB.
// MODE 1: QK^T split-K=2, split3, 128x128, BK=32, 1-D grid 1056 plain order,
//         packed-triangular f32 partials. LDS 32 KB.
// MODE 2: PV. A=P packed-triangular, B=Vt [DD,SQ], hi-only, 64x128, BK=64,
//         kend=(bmT+1)*128. grid (64,8), bm reversed = longest first. LDS 24 KB.
template<int MODE>
__global__ __launch_bounds__(256, 2)
void gemm_k(const f16* __restrict__ Ah, const f16* __restrict__ Al,
            const f16* __restrict__ Bh, const f16* __restrict__ Bl,
            float* __restrict__ Cf,
            f16* __restrict__ Qh, f16* __restrict__ Ql,
            f16* __restrict__ Kh, f16* __restrict__ Kl,
            f16* __restrict__ Vt, float scale)
{
    constexpr int TM = (MODE == 2) ? 64 : 128;
    constexpr int MI = 4;                         // 16-row frags per wave
    constexpr int NI = (MODE == 2) ? 2 : 4;       // 16-col frags per wave
    constexpr int H  = (MODE == 2) ? 2 : 1;       // BK/32 half-tiles
    constexpr int AH = TM * 32;                   // f16 per A half-tile
    constexpr int BH = 128 * 32;
    constexpr bool HAS_AL = (MODE != 2);          // A-lo tile may be staged
    constexpr bool HAS_BL = (MODE == 1);          // B-lo tile staged (split3 only)
    constexpr int SMSZ = H * AH + H * BH + (HAS_AL ? H * AH : 0) + (HAS_BL ? H * BH : 0);

    int bm, bn, tri = 0, half = 0;
    if (MODE == 1) {
        const int lin = blockIdx.x;               // plain order
        half = lin & 1;
        tri = lin >> 1;
        bm = (int)((sqrtf(8.f * (float)tri + 1.f) - 1.f) * 0.5f);
        while ((bm + 1) * (bm + 2) / 2 <= tri) ++bm;
        while (bm * (bm + 1) / 2 > tri) --bm;
        bn = tri - bm * (bm + 1) / 2;
    } else if (MODE == 2) {
        bm = 63 - (int)blockIdx.x;                // longest blocks first
        bn = blockIdx.y;
    } else {
        bn = blockIdx.x; bm = blockIdx.y;
    }

    const int m0 = bm * TM;
    const int n0 = bn << 7;
    const int lda = (MODE == 2) ? 128 : DD;       // MODE2 A = packed tile rows
    const int ldb = (MODE == 2) ? SQ : DD;
    const int kst = (MODE == 1) ? (half << 9) : 0;
    const int kend = (MODE == 1) ? (kst + 512)
                   : (MODE == 2) ? (((bm >> 1) + 1) << 7) : DD;
    const bool aLo = (MODE == 1) || (MODE == 0 && bn < 16);

    __shared__ f16 sm[SMSZ];
    f16* smA  = sm;
    f16* smB  = sm + H * AH;
    f16* smAl = smB + H * BH;                     // valid iff HAS_AL
    f16* smBl = smAl + (HAS_AL ? H * AH : 0);     // valid iff HAS_BL

    const int tid = threadIdx.x;
    const int w = tid >> 6, lane = tid & 63;
    const int wr = (MODE == 2) ? 0 : ((w >> 1) << 6);
    const int wc = (MODE == 2) ? (w << 5) : ((w & 1) << 6);
    const int fcol = lane & 15, quad = lane >> 4;

    f32x4 acc[MI][NI];
#pragma unroll
    for (int i = 0; i < MI; ++i)
#pragma unroll
        for (int j = 0; j < NI; ++j) acc[i][j] = (f32x4){0.f, 0.f, 0.f, 0.f};

    const int bmT = (MODE == 2) ? (bm >> 1) : 0;
    const size_t triRow = (MODE == 2) ? (size_t)(bmT * (bmT + 1) / 2) : 0;
    const f16* Bb  = Bh + (size_t)n0 * ldb;
    const f16* Abl = (HAS_AL && aLo) ? Al + (size_t)m0 * DD : nullptr;
    const f16* Bbl = HAS_BL ? Bl + (size_t)n0 * ldb : nullptr;

    for (int k0 = kst; k0 < kend; k0 += 32 * H) {
        __syncthreads();                          // prev iter's ds_reads done
#pragma unroll
        for (int h = 0; h < H; ++h) {
            const int kk = k0 + 32 * h;
            const f16* as;
            if (MODE == 2) {
                as = Ah + ((triRow + (size_t)(kk >> 7)) << 14)
                        + ((size_t)(m0 & 127) << 7) + (kk & 127);
            } else {
                as = Ah + (size_t)m0 * DD + kk;
            }
            stage<TM / 4>(as, lda, smA + h * AH, w, lane);
            stage<32>(Bb + kk, ldb, smB + h * BH, w, lane);
            if (HAS_AL && aLo) stage<TM / 4>(Abl + kk, DD, smAl + h * AH, w, lane);
            if (HAS_BL)        stage<32>(Bbl + kk, ldb, smBl + h * BH, w, lane);
        }
        __syncthreads();                          // vmcnt drained -> LDS valid

#pragma unroll
        for (int h = 0; h < H; ++h) {
            f16x8 bh[NI], bl[NI];
#pragma unroll
            for (int in = 0; in < NI; ++in) {
                const int off = ((wc + (in << 4) + fcol) << 5) + (quad << 3);
                bh[in] = *(const f16x8*)&smB[h * BH + off];
                if (HAS_BL) bl[in] = *(const f16x8*)&smBl[h * BH + off];
            }
#pragma unroll
            for (int im = 0; im < MI; ++im) {
                const int off = ((wr + (im << 4) + fcol) << 5) + (quad << 3);
                f16x8 ah = *(const f16x8*)&smA[h * AH + off];
                f16x8 al;
                if (HAS_AL && aLo) al = *(const f16x8*)&smAl[h * AH + off];
#pragma unroll
                for (int in = 0; in < NI; ++in) {
                    if (HAS_BL)
                        acc[im][in] = __builtin_amdgcn_mfma_f32_16x16x32_f16(ah, bl[in], acc[im][in], 0, 0, 0);
                    if (HAS_AL && aLo)
                        acc[im][in] = __builtin_amdgcn_mfma_f32_16x16x32_f16(al, bh[in], acc[im][in], 0, 0, 0);
                    acc[im][in] = __builtin_amdgcn_mfma_f32_16x16x32_f16(ah, bh[in], acc[im][in], 0, 0, 0);
                }
            }
        }
    }

    // C/D layout: col = lane&15, row = quad*4 + r  [m89-verified]
    if (MODE == 0) {
#pragma unroll
        for (int im = 0; im < MI; ++im) {
#pragma unroll
            for (int in = 0; in < NI; ++in) {
                const int region = bn >> 3;                       // 0=Q 1=K 2=V
                const int colL = ((bn & 7) << 7) + wc + (in << 4) + fcol;
                if (region == 2) {
                    const int tc = m0 + wr + (im << 4) + (quad << 2);
                    f16x4 o;
#pragma unroll
                    for (int r = 0; r < 4; ++r) o[r] = (f16)acc[im][in][r];
                    *(f16x4*)&Vt[(size_t)colL * SQ + tc] = o;
                } else {
                    f16* Hh = region ? Kh : Qh;
                    f16* Hl = region ? Kl : Ql;
#pragma unroll
                    for (int r = 0; r < 4; ++r) {
                        const int row = m0 + wr + (im << 4) + (quad << 2) + r;
                        const float v = acc[im][in][r];
                        const f16 h = (f16)v;
                        Hh[(size_t)row * DD + colL] = h;
                        Hl[(size_t)row * DD + colL] = (f16)(v - (float)h);
                    }
                }
            }
        }
    } else if (MODE == 1) {
        float* Cp = Cf + (((size_t)half * TRI + tri) << 14);
#pragma unroll
        for (int im = 0; im < MI; ++im) {
#pragma unroll
            for (int in = 0; in < NI; ++in) {
                const int cl = wc + (in << 4) + fcol;
#pragma unroll
                for (int r = 0; r < 4; ++r) {
                    const int rl = wr + (im << 4) + (quad << 2) + r;
                    Cp[(rl << 7) + cl] = acc[im][in][r] * scale;
                }
            }
        }
    } else {
#pragma unroll
        for (int im = 0; im < MI; ++im) {
#pragma unroll
            for (int in = 0; in < NI; ++in) {
#pragma unroll
                for (int r = 0; r < 4; ++r) {
                    const int row = m0 + wr + (im << 4) + (quad << 2) + r;
                    const int col = n0 + wc + (in << 4) + fcol;
                    Cf[(size_t)row * DD + col] = acc[im][in][r];
                }
            }
        }
    }
}

// Fused pre-pass: blocks [0,4096) split x into f16 hi/lo; blocks [4096,4864)
// transpose the 3 weight matrices into one [3072,1024] f16 buffer (hi only).
__global__ __launch_bounds__(256)
void prepass(const float* __restrict__ x,
             const float* __restrict__ W0, const float* __restrict__ W1,
             const float* __restrict__ W2,
             f16* __restrict__ xh, f16* __restrict__ xl,
             f16* __restrict__ Th0)
{
    __shared__ float t[64][65];
    const int id = blockIdx.x;
    const int tid = threadIdx.x;

    if (id < 4096) {
        const int i = (id * 256 + tid) * 4;
        const float4 v = *(const float4*)(x + i);
        const f16 h0 = (f16)v.x, h1 = (f16)v.y, h2 = (f16)v.z, h3 = (f16)v.w;
        f16x4 hv = {h0, h1, h2, h3};
        f16x4 lv = {(f16)(v.x - (float)h0), (f16)(v.y - (float)h1),
                    (f16)(v.z - (float)h2), (f16)(v.w - (float)h3)};
        *(f16x4*)(xh + i) = hv;
        *(f16x4*)(xl + i) = lv;
        return;
    }

    const int tt = id - 4096;
    const int z = tt >> 8, r8 = tt & 255;
    const float* W = (z == 0) ? W0 : (z == 1) ? W1 : W2;
    f16* Th = Th0 + (size_t)z * DD * DD;
    const int n0 = (r8 & 15) << 6, k0 = (r8 >> 4) << 6;
    const int tx = tid & 63, ty = tid >> 6;
    for (int r = ty; r < 64; r += 4) t[r][tx] = W[(size_t)(k0 + r) * DD + n0 + tx];
    __syncthreads();
    for (int r = ty; r < 64; r += 4)
        Th[(size_t)(n0 + r) * DD + k0 + tx] = (f16)t[tx][r];
}

// Row-wise causal softmax over packed-triangular split-K partials, vectorized:
// float4 loads of both partials, f16x4 P stores. At ~4.8 TB/s effective this
// kernel is at the memory roofline.
__global__ __launch_bounds__(256)
void softmax_causal(const float* __restrict__ A0, f16* __restrict__ P)
{
    const int i = blockIdx.x;
    const int n = i + 1;
    const int tid = threadIdx.x, w = tid >> 6, lane = tid & 63;
    __shared__ float redM[4], redS[4];
    __shared__ float rowbuf[SQ];                 // 16 KB merged-logit stash

    const int bmI = i >> 7;
    const size_t base = ((size_t)(bmI * (bmI + 1) / 2) << 14) + ((size_t)(i & 127) << 7);
    const float* A1 = A0 + ((size_t)TRI << 14);

    const int nv = n >> 2;                       // full float4 groups
    float m = -INFINITY;
    for (int g = tid; g < nv; g += 256) {
        const int j = g << 2;
        const size_t a = base + ((size_t)(j >> 7) << 14) + (j & 127);
        const float4 v0 = *(const float4*)(A0 + a);
        const float4 v1 = *(const float4*)(A1 + a);
        float4 v = make_float4(v0.x + v1.x, v0.y + v1.y, v0.z + v1.z, v0.w + v1.w);
        *(f32x4*)&rowbuf[j] = (f32x4){v.x, v.y, v.z, v.w};
        m = fmaxf(m, fmaxf(fmaxf(v.x, v.y), fmaxf(v.z, v.w)));
    }
    for (int j = (nv << 2) + tid; j < n; j += 256) {
        const size_t a = base + ((size_t)(j >> 7) << 14) + (j & 127);
        const float v = A0[a] + A1[a];
        rowbuf[j] = v;
        m = fmaxf(m, v);
    }
    m = waveMax(m);
    if (lane == 0) redM[w] = m;
    __syncthreads();
    const float mAll = fmaxf(fmaxf(redM[0], redM[1]), fmaxf(redM[2], redM[3]));

    float s = 0.f;
    for (int g = tid; g < nv; g += 256) {
        const int j = g << 2;
        f32x4 v = *(f32x4*)&rowbuf[j];
        v[0] = __expf(v[0] - mAll); v[1] = __expf(v[1] - mAll);
        v[2] = __expf(v[2] - mAll); v[3] = __expf(v[3] - mAll);
        *(f32x4*)&rowbuf[j] = v;
        s += v[0] + v[1] + v[2] + v[3];
    }
    for (int j = (nv << 2) + tid; j < n; j += 256) {
        const float e = __expf(rowbuf[j] - mAll);
        rowbuf[j] = e;
        s += e;
    }
    s = waveSum(s);
    if (lane == 0) redS[w] = s;
    __syncthreads();
    const float inv = 1.0f / (redS[0] + redS[1] + redS[2] + redS[3]);

    const int kmax = (bmI + 1) << 7;             // P zero-fill boundary
    for (int g = tid; g < nv; g += 256) {
        const int j = g << 2;
        const size_t a = base + ((size_t)(j >> 7) << 14) + (j & 127);
        const f32x4 v = *(const f32x4*)&rowbuf[j];
        f16x4 o = {(f16)(v[0] * inv), (f16)(v[1] * inv),
                   (f16)(v[2] * inv), (f16)(v[3] * inv)};
        *(f16x4*)&P[a] = o;
    }
    for (int j = (nv << 2) + tid; j < kmax; j += 256) {
        const size_t a = base + ((size_t)(j >> 7) << 14) + (j & 127);
        P[a] = (j < n) ? (f16)(rowbuf[j] * inv) : (f16)0.f;
    }
}

extern "C" void kernel_launch(void* const* d_in, const int* in_sizes, int n_in,
                              void* d_out, int out_size, void* d_ws, size_t ws_size,
                              hipStream_t stream)
{
    const float* x  = (const float*)d_in[0];
    const float* Wq = (const float*)d_in[1];
    const float* Wk = (const float*)d_in[2];
    const float* Wv = (const float*)d_in[3];
    float* out = (float*)d_out;

    // workspace carve (~149 MB)
    char* p = (char*)d_ws;
    auto take = [&](size_t bytes) { void* r = (void*)p; p += (bytes + 255) & ~(size_t)255; return r; };
    const size_t SD = (size_t)SQ * DD;          // 4M elems
    f16* xh  = (f16*)take(SD * 2);
    f16* xl  = (f16*)take(SD * 2);
    f16* Wth = (f16*)take((size_t)3 * DD * DD * 2);   // [3072][1024], hi only
    f16* Qh  = (f16*)take(SD * 2);
    f16* Ql  = (f16*)take(SD * 2);
    f16* Kh  = (f16*)take(SD * 2);
    f16* Kl  = (f16*)take(SD * 2);
    f16* Vt  = (f16*)take(SD * 2);              // [DD][SQ]
    float* attn = (float*)take((size_t)2 * TRI * 16384 * 4);  // split-K partials, packed
    f16* P   = (f16*)take((size_t)TRI * 16384 * 2);           // packed triangular

    const dim3 blk(256);

    prepass<<<dim3(4096 + 768), blk, 0, stream>>>(x, Wq, Wk, Wv, xh, xl, Wth);

    // Merged QKV projection: 768 blocks, BK=32, x-split 2-MFMA (W plain f16)
    gemm_k<0><<<dim3(24, SQ / 128), blk, 0, stream>>>(
        xh, xl, Wth, nullptr, nullptr, Qh, Ql, Kh, Kl, Vt, 1.0f);

    // attn partials = Q @ K^T / 32 : split-K=2, split3, 128x128, 1056 blocks
    gemm_k<1><<<dim3(2 * TRI), blk, 0, stream>>>(
        Qh, Ql, Kh, Kl, attn, nullptr, nullptr, nullptr, nullptr, nullptr, 0.03125f);

    softmax_causal<<<dim3(SQ), blk, 0, stream>>>(attn, P);

    // out = P @ V : grid (64,8), longest-first
    gemm_k<2><<<dim3(SQ / 64, DD / 128), blk, 0, stream>>>(
        P, nullptr, Vt, nullptr, out, nullptr, nullptr, nullptr, nullptr, nullptr, 1.0f);
}